// Round 10
// baseline (374.034 us; speedup 1.0000x reference)
//
#include <hip/hip_runtime.h>

#define D 64
#define CAP 56     // per-node bucket capacity; P(Poisson(16) >= 56) ~ 1e-13
#define NB 256     // scatter chunk blocks (hist/off rows)
#define LSLOT 3584 // per-slice edge-log capacity (avg fill ~1024)

// R22 MEASUREMENT ROUND (R21 redo, race-fixed): replicate kernels to surface
// them in the rocprof top-5 (cutoff ~43us = harness fill). R21 failed because
// bucketize's output permutation is LDS-atomic-order-dependent -> replicas
// produced DIFFERENT permutations whose racing writebacks mixed into a wrong
// multiset. Fix: replica r=0 writes real outputs; r>=1 write a shared scratch
// region that is NEVER read (races there harmless). Unit cost = dur / REP.
#define GREP 6     // gather replicas
#define DREP 6     // dense replicas
#define BREP 8     // bucketize replicas

typedef __attribute__((ext_vector_type(8))) short short8;   // 8 bf16 (4 VGPRs)
typedef __attribute__((ext_vector_type(4))) float f32x4;

__device__ __forceinline__ unsigned short f2bf(float f) {
    unsigned u = __float_as_uint(f);
    u = (u + 0x7fff + ((u >> 16) & 1)) >> 16;   // RNE
    return (unsigned short)u;
}
__device__ __forceinline__ float bf_lo(unsigned u) { return __uint_as_float(u << 16); }
__device__ __forceinline__ float bf_hi(unsigned u) { return __uint_as_float(u & 0xffff0000u); }

// R20 (kept): deterministic two-pass counting scatter — zero global atomics.
__global__ __launch_bounds__(256) void count_conv_prep(
    const int* __restrict__ dst, int* __restrict__ hist,
    int n_edges, int chunk, int S,
    const float* __restrict__ x, unsigned short* __restrict__ xb,
    int n4, int n4p, int ncb,
    const float* __restrict__ w1_0, const float* __restrict__ w2_0,
    const float* __restrict__ w1_1, const float* __restrict__ w2_1,
    unsigned short* __restrict__ wt)
{
    const int b   = blockIdx.x;
    const int tid = threadIdx.x;

    if (b < NB) {
        __shared__ int cnt[784];
        for (int j = tid; j < 784; j += 256) cnt[j] = 0;
        __syncthreads();
        const int e0 = b * chunk;
        const int e1 = (e0 + chunk < n_edges) ? e0 + chunk : n_edges;
        for (int i = e0 + tid; i < e1; i += 256)
            atomicAdd(&cnt[dst[i] >> 6], 1);          // LDS atomic (per-CU, cheap)
        __syncthreads();
        for (int j = tid; j < S; j += 256)
            hist[b * S + j] = cnt[j];                 // coalesced private row
    } else if (b < NB + ncb) {
        int i = (b - NB) * 256 + tid;
        if (i < n4) {
            f32x4 v = __builtin_nontemporal_load((const f32x4*)(x + (size_t)i * 4));
            ushort4 o;
            o.x = f2bf(v.x); o.y = f2bf(v.y); o.z = f2bf(v.z); o.w = f2bf(v.w);
            *(ushort4*)(xb + (size_t)i * 4) = o;
        } else if (i < n4p) {
            *(ushort4*)(xb + (size_t)i * 4) = make_ushort4(0, 0, 0, 0);  // pad rows
        }
    } else {
        int i = (b - NB - ncb) * 256 + tid;   // 0..16383
        int m = i >> 12, r = i & 4095;
        int n = r >> 6, k = r & 63;
        const float* w = (m == 0) ? w1_0 : (m == 1) ? w2_0 : (m == 2) ? w1_1 : w2_1;
        wt[i] = f2bf(w[k * 64 + n]);
    }
}

// R20 (kept): per-slice exclusive scan over the NB block-histogram entries.
__global__ __launch_bounds__(256) void prefix_kernel(
    const int* __restrict__ hist, int* __restrict__ off,
    unsigned* __restrict__ gcur, int S)
{
    __shared__ int wsum[4];
    const int sl = blockIdx.x;
    const int t  = threadIdx.x;
    const int lane = t & 63, wv = t >> 6;

    int v  = hist[t * S + sl];
    int xs = v;
    #pragma unroll
    for (int o = 1; o < 64; o <<= 1) {
        int y = __shfl_up(xs, o, 64);
        if (lane >= o) xs += y;
    }
    if (lane == 63) wsum[wv] = xs;
    __syncthreads();
    int wo = 0;
    for (int w = 0; w < wv; ++w) wo += wsum[w];
    off[t * S + sl] = wo + xs - v;
    if (t == 255) gcur[sl] = (unsigned)(wo + xs);
}

// R20 (kept): emit — single instance (atomic-order permutation is fine when
// only ONE writer exists; any order is a valid permutation).
__global__ __launch_bounds__(256) void emit_kernel(
    const int* __restrict__ src, const int* __restrict__ dst,
    const int* __restrict__ off, unsigned* __restrict__ elog,
    int n_edges, int chunk, int S)
{
    __shared__ int cur[784];
    const int b   = blockIdx.x;
    const int tid = threadIdx.x;

    for (int j = tid; j < S; j += 256) cur[j] = off[b * S + j];
    __syncthreads();

    const int e0 = b * chunk;
    const int e1 = (e0 + chunk < n_edges) ? e0 + chunk : n_edges;
    for (int i = e0 + tid; i < e1; i += 256) {
        int d = dst[i], s = src[i];
        int sl = d >> 6;
        int p = atomicAdd(&cur[sl], 1);               // LDS atomic rank
        if (p < LSLOT)
            elog[(size_t)sl * LSLOT + p] = ((unsigned)d << 16) | (unsigned)s;
    }
}

// R14 (kept, REPLICATED xBREP): slice bucket builder. Replica 0 writes real
// deg/buf; replicas >=1 write scratch (never read -> races harmless).
__global__ __launch_bounds__(256) void bucketize_kernel(
    const unsigned* __restrict__ gcur, const unsigned* __restrict__ elog,
    int* __restrict__ deg, unsigned short* __restrict__ buf,
    int* __restrict__ sdeg_scr, unsigned short* __restrict__ sbuf_scr, int nblk)
{
    __shared__ int sdeg[64];
    __shared__ unsigned short sbuf[64][CAP];   // 7168 B

    const int r   = blockIdx.x / nblk;
    const int g   = blockIdx.x % nblk;
    const int tid = threadIdx.x;

    int* dout            = (r == 0) ? deg : sdeg_scr;
    unsigned short* bout = (r == 0) ? buf : sbuf_scr;

    unsigned* zb = (unsigned*)&sbuf[0][0];
    for (int i = tid; i < 64 * CAP / 2; i += 256) zb[i] = 0;
    if (tid < 64) sdeg[tid] = 0;
    int cnt = (int)gcur[g]; if (cnt > LSLOT) cnt = LSLOT;
    __syncthreads();

    for (int i = tid; i < cnt; i += 256) {
        unsigned v = elog[(size_t)g * LSLOT + i];
        int dl = (v >> 16) & 63;
        int p  = atomicAdd(&sdeg[dl], 1);
        if (p < CAP) sbuf[dl][p] = (unsigned short)(v & 0xffffu);
    }
    __syncthreads();

    const unsigned* sb = (const unsigned*)&sbuf[0][0];
    unsigned* gbuf = (unsigned*)(bout + (size_t)g * 64 * CAP);
    for (int i = tid; i < 64 * CAP / 2; i += 256) gbuf[i] = sb[i];
    if (tid < 64) dout[g * 64 + tid] = sdeg[tid];
}

// R18 (kept, REPLICATED xGREP): two nodes per wave, all loads issued up-front.
// Replica 0 writes aggb; replicas >=1 write scratch.
__global__ __launch_bounds__(256) void gather_kernel(
    const unsigned short* __restrict__ xb, const int* __restrict__ deg,
    const unsigned short* __restrict__ buf, unsigned short* __restrict__ aggb,
    unsigned short* __restrict__ agg_scr, int nblk)
{
    const int tid  = threadIdx.x;
    const int lane = tid & 63;
    const int wave = tid >> 6;
    const int r    = blockIdx.x / nblk;
    const int bb   = blockIdx.x % nblk;
    const int n0   = bb * 8 + wave * 2;
    const int n1   = n0 + 1;
    unsigned short* outp = (r == 0) ? aggb : agg_scr;

    const int slot = lane >> 3;        // 0..7
    const int fc   = (lane & 7) << 3;  // bf16 offset 0,8,...,56 (16B per lane)
    const int li   = lane < CAP ? lane : CAP - 1;

    int idxA = buf[(size_t)n0 * CAP + li];
    int idxB = buf[(size_t)n1 * CAP + li];
    int ddA = deg[n0]; ddA = ddA < CAP ? ddA : CAP;
    int ddB = deg[n1]; ddB = ddB < CAP ? ddB : CAP;

    uint4 uA = make_uint4(0u, 0u, 0u, 0u), uB = uA;
    if (slot == 0) {
        uA = *(const uint4*)(xb + (size_t)n0 * D + fc);
        uB = *(const uint4*)(xb + (size_t)n1 * D + fc);
    }

    int sA[3], sB[3];
    #pragma unroll
    for (int g = 0; g < 3; ++g) {
        sA[g] = __shfl(idxA, (g << 3) + slot);
        sB[g] = __shfl(idxB, (g << 3) + slot);
    }

    uint4 vA0 = *(const uint4*)(xb + (size_t)sA[0] * D + fc);
    uint4 vA1 = *(const uint4*)(xb + (size_t)sA[1] * D + fc);
    uint4 vA2 = *(const uint4*)(xb + (size_t)sA[2] * D + fc);
    uint4 vB0 = *(const uint4*)(xb + (size_t)sB[0] * D + fc);
    uint4 vB1 = *(const uint4*)(xb + (size_t)sB[1] * D + fc);
    uint4 vB2 = *(const uint4*)(xb + (size_t)sB[2] * D + fc);

    float a[8] = {0.f, 0.f, 0.f, 0.f, 0.f, 0.f, 0.f, 0.f};
    float b[8] = {0.f, 0.f, 0.f, 0.f, 0.f, 0.f, 0.f, 0.f};

    if (ddA > 24) {   // wave-uniform, ~2% of nodes
        #pragma unroll
        for (int g = 3; g < 7; ++g) {
            int sg = __shfl(idxA, (g << 3) + slot);
            uint4 v = *(const uint4*)(xb + (size_t)sg * D + fc);
            float m = ((g << 3) + slot) < ddA ? 1.0f : 0.0f;
            a[0] += bf_lo(v.x) * m; a[1] += bf_hi(v.x) * m;
            a[2] += bf_lo(v.y) * m; a[3] += bf_hi(v.y) * m;
            a[4] += bf_lo(v.z) * m; a[5] += bf_hi(v.z) * m;
            a[6] += bf_lo(v.w) * m; a[7] += bf_hi(v.w) * m;
        }
    }
    if (ddB > 24) {   // wave-uniform, ~2% of nodes
        #pragma unroll
        for (int g = 3; g < 7; ++g) {
            int sg = __shfl(idxB, (g << 3) + slot);
            uint4 v = *(const uint4*)(xb + (size_t)sg * D + fc);
            float m = ((g << 3) + slot) < ddB ? 1.0f : 0.0f;
            b[0] += bf_lo(v.x) * m; b[1] += bf_hi(v.x) * m;
            b[2] += bf_lo(v.y) * m; b[3] += bf_hi(v.y) * m;
            b[4] += bf_lo(v.z) * m; b[5] += bf_hi(v.z) * m;
            b[6] += bf_lo(v.w) * m; b[7] += bf_hi(v.w) * m;
        }
    }

    {   // node A: groups 0-2 (masked) + self
        float m0 = (slot      < ddA) ? 1.0f : 0.0f;
        float m1 = (slot +  8 < ddA) ? 1.0f : 0.0f;
        float m2 = (slot + 16 < ddA) ? 1.0f : 0.0f;
        a[0] += bf_lo(vA0.x) * m0 + bf_lo(vA1.x) * m1 + bf_lo(vA2.x) * m2 + bf_lo(uA.x);
        a[1] += bf_hi(vA0.x) * m0 + bf_hi(vA1.x) * m1 + bf_hi(vA2.x) * m2 + bf_hi(uA.x);
        a[2] += bf_lo(vA0.y) * m0 + bf_lo(vA1.y) * m1 + bf_lo(vA2.y) * m2 + bf_lo(uA.y);
        a[3] += bf_hi(vA0.y) * m0 + bf_hi(vA1.y) * m1 + bf_hi(vA2.y) * m2 + bf_hi(uA.y);
        a[4] += bf_lo(vA0.z) * m0 + bf_lo(vA1.z) * m1 + bf_lo(vA2.z) * m2 + bf_lo(uA.z);
        a[5] += bf_hi(vA0.z) * m0 + bf_hi(vA1.z) * m1 + bf_hi(vA2.z) * m2 + bf_hi(uA.z);
        a[6] += bf_lo(vA0.w) * m0 + bf_lo(vA1.w) * m1 + bf_lo(vA2.w) * m2 + bf_lo(uA.w);
        a[7] += bf_hi(vA0.w) * m0 + bf_hi(vA1.w) * m1 + bf_hi(vA2.w) * m2 + bf_hi(uA.w);
    }
    {   // node B: groups 0-2 (masked) + self
        float m0 = (slot      < ddB) ? 1.0f : 0.0f;
        float m1 = (slot +  8 < ddB) ? 1.0f : 0.0f;
        float m2 = (slot + 16 < ddB) ? 1.0f : 0.0f;
        b[0] += bf_lo(vB0.x) * m0 + bf_lo(vB1.x) * m1 + bf_lo(vB2.x) * m2 + bf_lo(uB.x);
        b[1] += bf_hi(vB0.x) * m0 + bf_hi(vB1.x) * m1 + bf_hi(vB2.x) * m2 + bf_hi(uB.x);
        b[2] += bf_lo(vB0.y) * m0 + bf_lo(vB1.y) * m1 + bf_lo(vB2.y) * m2 + bf_lo(uB.y);
        b[3] += bf_hi(vB0.y) * m0 + bf_hi(vB1.y) * m1 + bf_hi(vB2.y) * m2 + bf_hi(uB.y);
        b[4] += bf_lo(vB0.z) * m0 + bf_lo(vB1.z) * m1 + bf_lo(vB2.z) * m2 + bf_lo(uB.z);
        b[5] += bf_hi(vB0.z) * m0 + bf_hi(vB1.z) * m1 + bf_hi(vB2.z) * m2 + bf_hi(uB.z);
        b[6] += bf_lo(vB0.w) * m0 + bf_lo(vB1.w) * m1 + bf_lo(vB2.w) * m2 + bf_lo(uB.w);
        b[7] += bf_hi(vB0.w) * m0 + bf_hi(vB1.w) * m1 + bf_hi(vB2.w) * m2 + bf_hi(uB.w);
    }

    #pragma unroll
    for (int m = 8; m <= 32; m <<= 1) {
        #pragma unroll
        for (int q = 0; q < 8; ++q) { a[q] += __shfl_xor(a[q], m); b[q] += __shfl_xor(b[q], m); }
    }
    if (slot == 0) {
        uint4 o;
        o.x = (unsigned)f2bf(a[0]) | ((unsigned)f2bf(a[1]) << 16);
        o.y = (unsigned)f2bf(a[2]) | ((unsigned)f2bf(a[3]) << 16);
        o.z = (unsigned)f2bf(a[4]) | ((unsigned)f2bf(a[5]) << 16);
        o.w = (unsigned)f2bf(a[6]) | ((unsigned)f2bf(a[7]) << 16);
        *(uint4*)(outp + (size_t)n0 * D + fc) = o;
        o.x = (unsigned)f2bf(b[0]) | ((unsigned)f2bf(b[1]) << 16);
        o.y = (unsigned)f2bf(b[2]) | ((unsigned)f2bf(b[3]) << 16);
        o.z = (unsigned)f2bf(b[4]) | ((unsigned)f2bf(b[5]) << 16);
        o.w = (unsigned)f2bf(b[6]) | ((unsigned)f2bf(b[7]) << 16);
        *(uint4*)(outp + (size_t)n1 * D + fc) = o;
    }
}

// dense (REPLICATED xDREP): replica 0 writes real output; others scratch.
template <bool WRITE_BF16>
__global__ __launch_bounds__(256) void gin_dense_mfma(
    const unsigned short* __restrict__ hb, int n_nodes,
    const unsigned short* __restrict__ w1t, const float* __restrict__ b1,
    const unsigned short* __restrict__ w2t, const float* __restrict__ b2,
    float* __restrict__ out_f, unsigned short* __restrict__ out_b,
    float* __restrict__ scr_f, unsigned short* __restrict__ scr_b, int nblk)
{
    __shared__ unsigned short sh [64][72];
    __shared__ unsigned short st [64][72];
    __shared__ unsigned short sw1[64][72];
    __shared__ unsigned short sw2[64][72];

    const int t    = threadIdx.x;
    const int lane = t & 63;
    const int wave = t >> 6;
    const int quad = lane >> 4;
    const int col  = lane & 15;
    const int rr   = blockIdx.x / nblk;
    const int nb   = (blockIdx.x % nblk) * 64;

    float* of          = (rr == 0) ? out_f : scr_f;
    unsigned short* ob = (rr == 0) ? out_b : scr_b;

    for (int c = t; c < 512; c += 256) {
        int row = c >> 3, c8 = (c & 7) << 3;
        *(uint4*)&sh [row][c8] = *(const uint4*)(hb  + (size_t)(nb + row) * D + c8);
        *(uint4*)&sw1[row][c8] = *(const uint4*)(w1t + row * D + c8);
        *(uint4*)&sw2[row][c8] = *(const uint4*)(w2t + row * D + c8);
    }
    __syncthreads();

    const int arow = 16 * wave + col;
    const int koff = quad << 3;

    short8 a0 = *(const short8*)&sh[arow][koff];
    short8 a1 = *(const short8*)&sh[arow][32 + koff];

    #pragma unroll
    for (int nt = 0; nt < 4; ++nt) {
        int n = (nt << 4) + col;
        short8 bw0 = *(const short8*)&sw1[n][koff];
        short8 bw1 = *(const short8*)&sw1[n][32 + koff];
        float bv = b1[n];
        f32x4 c = {bv, bv, bv, bv};
        c = __builtin_amdgcn_mfma_f32_16x16x32_bf16(a0, bw0, c, 0, 0, 0);
        c = __builtin_amdgcn_mfma_f32_16x16x32_bf16(a1, bw1, c, 0, 0, 0);
        #pragma unroll
        for (int r = 0; r < 4; ++r)
            st[16 * wave + (quad << 2) + r][n] = f2bf(tanhf(c[r]));
    }
    // no __syncthreads: each wave reads back exactly the rows it wrote

    short8 p0 = *(const short8*)&st[arow][koff];
    short8 p1 = *(const short8*)&st[arow][32 + koff];

    #pragma unroll
    for (int nt = 0; nt < 4; ++nt) {
        int n = (nt << 4) + col;
        short8 bw0 = *(const short8*)&sw2[n][koff];
        short8 bw1 = *(const short8*)&sw2[n][32 + koff];
        float bv = b2[n];
        f32x4 c = {bv, bv, bv, bv};
        c = __builtin_amdgcn_mfma_f32_16x16x32_bf16(p0, bw0, c, 0, 0, 0);
        c = __builtin_amdgcn_mfma_f32_16x16x32_bf16(p1, bw1, c, 0, 0, 0);
        #pragma unroll
        for (int r = 0; r < 4; ++r) {
            int row = nb + 16 * wave + (quad << 2) + r;
            if (WRITE_BF16) {
                ob[(size_t)row * D + n] = f2bf(c[r]);   // sized n_pad: no clamp
            } else if (row < n_nodes) {
                of[(size_t)row * D + n] = c[r];
            }
        }
    }
}

extern "C" void kernel_launch(void* const* d_in, const int* in_sizes, int n_in,
                              void* d_out, int out_size, void* d_ws, size_t ws_size,
                              hipStream_t stream)
{
    const float* x    = (const float*)d_in[0];
    const int*   src  = (const int*)  d_in[1];
    const int*   dst  = (const int*)  d_in[2];
    const float* w1_0 = (const float*)d_in[3];
    const float* b1_0 = (const float*)d_in[4];
    const float* w2_0 = (const float*)d_in[5];
    const float* b2_0 = (const float*)d_in[6];
    const float* w1_1 = (const float*)d_in[7];
    const float* b1_1 = (const float*)d_in[8];
    const float* w2_1 = (const float*)d_in[9];
    const float* b2_1 = (const float*)d_in[10];
    float* out = (float*)d_out;

    const int n_nodes = in_sizes[0] / D;        // 50000
    const int n_edges = in_sizes[1];            // 800000
    const int n_pad   = (n_nodes + 63) & ~63;   // 50048
    const int S       = n_pad >> 6;             // 782 slices of 64 nodes
    const int chunk   = (n_edges + NB - 1) / NB;   // 3125

    // ws: hist | off | gcur | elog | deg | buf | aggb | xb | x1b | wt | scratch
    int*            hist = (int*)d_ws;
    int*            off  = hist + (size_t)NB * S;
    unsigned*       gcur = (unsigned*)(off + (size_t)NB * S);
    unsigned*       elog = gcur + S;
    int*            deg  = (int*)(elog + (size_t)S * LSLOT);
    unsigned short* buf  = (unsigned short*)(deg + n_pad);
    unsigned short* aggb = buf  + (size_t)n_pad * CAP;
    unsigned short* xb   = aggb + (size_t)n_pad * D;
    unsigned short* x1b  = xb   + (size_t)n_pad * D;
    unsigned short* wt   = x1b  + (size_t)n_pad * D;
    // scratch (~13 MB): dump target for replicas >=1; NEVER read.
    unsigned short* scr  = wt + 16384;
    int*            scr_deg = (int*)scr;                      // aliases fine
    unsigned short* scr_buf = scr + 2 * (size_t)n_pad;        // after deg-sized gap
    float*          scr_f   = (float*)scr;
    unsigned short* scr_b   = scr;

    const int n4  = n_nodes * D / 4;             // 800000
    const int n4p = n_pad * D / 4;               // 800768 (pad rows zeroed)
    const int ncb = (n4p + 255) / 256;

    count_conv_prep<<<NB + ncb + 64, 256, 0, stream>>>(
        dst, hist, n_edges, chunk, S,
        x, xb, n4, n4p, ncb,
        w1_0, w2_0, w1_1, w2_1, wt);
    prefix_kernel<<<S, 256, 0, stream>>>(hist, off, gcur, S);
    emit_kernel<<<NB, 256, 0, stream>>>(src, dst, off, elog, n_edges, chunk, S);
    bucketize_kernel<<<S * BREP, 256, 0, stream>>>(
        gcur, elog, deg, buf, scr_deg, scr_buf, S);

    const int gather_blocks = n_pad / 8;      // 6256 (2 nodes/wave)
    const int dense_blocks  = n_pad / 64;     // 782

    // layer 0 (gather x6, dense x6 — replica 0 real, rest scratch)
    gather_kernel<<<gather_blocks * GREP, 256, 0, stream>>>(
        xb, deg, buf, aggb, scr_b, gather_blocks);
    gin_dense_mfma<true><<<dense_blocks * DREP, 256, 0, stream>>>(
        aggb, n_nodes, wt, b1_0, wt + 4096, b2_0, nullptr, x1b,
        scr_f, scr_b, dense_blocks);
    // layer 1
    gather_kernel<<<gather_blocks * GREP, 256, 0, stream>>>(
        x1b, deg, buf, aggb, scr_b, gather_blocks);
    gin_dense_mfma<false><<<dense_blocks * DREP, 256, 0, stream>>>(
        aggb, n_nodes, wt + 8192, b1_1, wt + 12288, b2_1, out, nullptr,
        scr_f, scr_b, dense_blocks);
}

// Round 11
// 165.384 us; speedup vs baseline: 2.2616x; 2.2616x over previous
//
#include <hip/hip_runtime.h>

#define D 64
#define CAP 56     // per-node bucket capacity (incl. self); P(Poisson(16)+1 > 56) ~ 1e-13
#define NB 256     // scatter chunk blocks (hist/off rows)
#define LSLOT 3584 // per-slice edge-log capacity (avg fill ~1024)

typedef __attribute__((ext_vector_type(8))) short short8;   // 8 bf16 (4 VGPRs)
typedef __attribute__((ext_vector_type(4))) float f32x4;

__device__ __forceinline__ unsigned short f2bf(float f) {
    unsigned u = __float_as_uint(f);
    u = (u + 0x7fff + ((u >> 16) & 1)) >> 16;   // RNE
    return (unsigned short)u;
}
__device__ __forceinline__ float bf_lo(unsigned u) { return __uint_as_float(u << 16); }
__device__ __forceinline__ float bf_hi(unsigned u) { return __uint_as_float(u & 0xffff0000u); }

// R20 (kept): deterministic two-pass counting scatter — zero global atomics.
//  [0, NB)             : count   — LDS histogram of chunk b, row write
//  [NB, NB+ncb)        : convert — x fp32 -> xb bf16 (pad rows zeroed)
//  [NB+ncb, +64)       : prep    — 4 weight mats -> bf16 transposed
__global__ __launch_bounds__(256) void count_conv_prep(
    const int* __restrict__ dst, int* __restrict__ hist,
    int n_edges, int chunk, int S,
    const float* __restrict__ x, unsigned short* __restrict__ xb,
    int n4, int n4p, int ncb,
    const float* __restrict__ w1_0, const float* __restrict__ w2_0,
    const float* __restrict__ w1_1, const float* __restrict__ w2_1,
    unsigned short* __restrict__ wt)
{
    const int b   = blockIdx.x;
    const int tid = threadIdx.x;

    if (b < NB) {
        __shared__ int cnt[784];
        for (int j = tid; j < 784; j += 256) cnt[j] = 0;
        __syncthreads();
        const int e0 = b * chunk;
        const int e1 = (e0 + chunk < n_edges) ? e0 + chunk : n_edges;
        for (int i = e0 + tid; i < e1; i += 256)
            atomicAdd(&cnt[dst[i] >> 6], 1);          // LDS atomic (per-CU, cheap)
        __syncthreads();
        for (int j = tid; j < S; j += 256)
            hist[b * S + j] = cnt[j];                 // coalesced private row
    } else if (b < NB + ncb) {
        int i = (b - NB) * 256 + tid;
        if (i < n4) {
            f32x4 v = __builtin_nontemporal_load((const f32x4*)(x + (size_t)i * 4));
            ushort4 o;
            o.x = f2bf(v.x); o.y = f2bf(v.y); o.z = f2bf(v.z); o.w = f2bf(v.w);
            *(ushort4*)(xb + (size_t)i * 4) = o;
        } else if (i < n4p) {
            *(ushort4*)(xb + (size_t)i * 4) = make_ushort4(0, 0, 0, 0);  // pad rows = 0
        }
    } else {
        int i = (b - NB - ncb) * 256 + tid;   // 0..16383
        int m = i >> 12, r = i & 4095;
        int n = r >> 6, k = r & 63;
        const float* w = (m == 0) ? w1_0 : (m == 1) ? w2_0 : (m == 2) ? w1_1 : w2_1;
        wt[i] = f2bf(w[k * 64 + n]);
    }
}

// R20 (kept): per-slice exclusive scan over the NB block-histogram entries.
__global__ __launch_bounds__(256) void prefix_kernel(
    const int* __restrict__ hist, int* __restrict__ off,
    unsigned* __restrict__ gcur, int S)
{
    __shared__ int wsum[4];
    const int sl = blockIdx.x;
    const int t  = threadIdx.x;
    const int lane = t & 63, wv = t >> 6;

    int v  = hist[t * S + sl];
    int xs = v;
    #pragma unroll
    for (int o = 1; o < 64; o <<= 1) {
        int y = __shfl_up(xs, o, 64);
        if (lane >= o) xs += y;
    }
    if (lane == 63) wsum[wv] = xs;
    __syncthreads();
    int wo = 0;
    for (int w = 0; w < wv; ++w) wo += wsum[w];
    off[t * S + sl] = wo + xs - v;
    if (t == 255) gcur[sl] = (unsigned)(wo + xs);
}

// R20 (kept): emit — write packed edges at deterministic disjoint ranges.
__global__ __launch_bounds__(256) void emit_kernel(
    const int* __restrict__ src, const int* __restrict__ dst,
    const int* __restrict__ off, unsigned* __restrict__ elog,
    int n_edges, int chunk, int S)
{
    __shared__ int cur[784];
    const int b   = blockIdx.x;
    const int tid = threadIdx.x;

    for (int j = tid; j < S; j += 256) cur[j] = off[b * S + j];
    __syncthreads();

    const int e0 = b * chunk;
    const int e1 = (e0 + chunk < n_edges) ? e0 + chunk : n_edges;
    for (int i = e0 + tid; i < e1; i += 256) {
        int d = dst[i], s = src[i];
        int sl = d >> 6;
        int p = atomicAdd(&cur[sl], 1);               // LDS atomic rank
        if (p < LSLOT)
            elog[(size_t)sl * LSLOT + p] = ((unsigned)d << 16) | (unsigned)s;
    }
}

// R23: bucket builder. Two changes vs R14:
//  (1) unused slots filled with PADIDX (= n_nodes, a ZEROED row) instead of 0
//      -> gather needs no masks, and wasted loads hit one L2-hot line;
//  (2) each node APPENDS ITSELF to its bucket -> gather's divergent self-load
//      and its unpack-add chain deleted. deg array eliminated entirely
//      (gather's tail test = bucket[24] != PADIDX, in-register).
__global__ __launch_bounds__(256) void bucketize_kernel(
    const unsigned* __restrict__ gcur, const unsigned* __restrict__ elog,
    unsigned short* __restrict__ buf, int padidx)
{
    __shared__ int sdeg[64];
    __shared__ unsigned short sbuf[64][CAP];   // 7168 B

    const int g   = blockIdx.x;
    const int tid = threadIdx.x;

    const unsigned fillw = ((unsigned)padidx << 16) | (unsigned)padidx;
    unsigned* zb = (unsigned*)&sbuf[0][0];
    for (int i = tid; i < 64 * CAP / 2; i += 256) zb[i] = fillw;
    if (tid < 64) sdeg[tid] = 0;
    int cnt = (int)gcur[g]; if (cnt > LSLOT) cnt = LSLOT;
    __syncthreads();

    for (int i = tid; i < cnt; i += 256) {
        unsigned v = elog[(size_t)g * LSLOT + i];
        int dl = (v >> 16) & 63;
        int p  = atomicAdd(&sdeg[dl], 1);
        if (p < CAP) sbuf[dl][p] = (unsigned short)(v & 0xffffu);
    }
    __syncthreads();

    if (tid < 64) {   // append self (entry count = deg+1)
        int p = sdeg[tid];
        if (p < CAP) sbuf[tid][p] = (unsigned short)(g * 64 + tid);
    }
    __syncthreads();

    const unsigned* sb = (const unsigned*)&sbuf[0][0];
    unsigned* gbuf = (unsigned*)(buf + (size_t)g * 64 * CAP);
    for (int i = tid; i < 64 * CAP / 2; i += 256) gbuf[i] = sb[i];
}

// agg[n] = sum_{s in bucket[n]} xb[s]   (bucket includes self; PADIDX entries
// hit the zeroed pad row -> contribute 0; its 128B line stays L2-hot).
// R23: mask-free, deg-free. Two nodes/wave (R18), all loads issued up-front.
// Tail (entries > 24, ~2% of nodes): wave-uniform in-register test, mask-free.
__global__ __launch_bounds__(256) void gather_kernel(
    const unsigned short* __restrict__ xb,
    const unsigned short* __restrict__ buf, unsigned short* __restrict__ aggb,
    int padidx)
{
    const int tid  = threadIdx.x;
    const int lane = tid & 63;
    const int wave = tid >> 6;
    const int n0   = blockIdx.x * 8 + wave * 2;
    const int n1   = n0 + 1;

    const int slot = lane >> 3;        // 0..7
    const int fc   = (lane & 7) << 3;  // bf16 offset 0,8,...,56 (16B per lane)
    const int li   = lane < CAP ? lane : CAP - 1;

    int idxA = buf[(size_t)n0 * CAP + li];
    int idxB = buf[(size_t)n1 * CAP + li];

    int sA[3], sB[3];
    #pragma unroll
    for (int g = 0; g < 3; ++g) {
        sA[g] = __shfl(idxA, (g << 3) + slot);
        sB[g] = __shfl(idxB, (g << 3) + slot);
    }

    // 6 independent row loads, back-to-back issue (cover entries 0..23)
    uint4 vA0 = *(const uint4*)(xb + (size_t)sA[0] * D + fc);
    uint4 vA1 = *(const uint4*)(xb + (size_t)sA[1] * D + fc);
    uint4 vA2 = *(const uint4*)(xb + (size_t)sA[2] * D + fc);
    uint4 vB0 = *(const uint4*)(xb + (size_t)sB[0] * D + fc);
    uint4 vB1 = *(const uint4*)(xb + (size_t)sB[1] * D + fc);
    uint4 vB2 = *(const uint4*)(xb + (size_t)sB[2] * D + fc);

    float a[8] = {0.f, 0.f, 0.f, 0.f, 0.f, 0.f, 0.f, 0.f};
    float b[8] = {0.f, 0.f, 0.f, 0.f, 0.f, 0.f, 0.f, 0.f};

    // tail: entry 24 occupied <=> more than 24 entries (wave-uniform)
    int tA = __shfl(idxA, 24);
    int tB = __shfl(idxB, 24);

    if (tA != padidx) {   // ~2% of nodes
        #pragma unroll
        for (int g = 3; g < 7; ++g) {
            int sg = __shfl(idxA, (g << 3) + slot);
            uint4 v = *(const uint4*)(xb + (size_t)sg * D + fc);
            a[0] += bf_lo(v.x); a[1] += bf_hi(v.x);
            a[2] += bf_lo(v.y); a[3] += bf_hi(v.y);
            a[4] += bf_lo(v.z); a[5] += bf_hi(v.z);
            a[6] += bf_lo(v.w); a[7] += bf_hi(v.w);
        }
    }
    if (tB != padidx) {   // ~2% of nodes
        #pragma unroll
        for (int g = 3; g < 7; ++g) {
            int sg = __shfl(idxB, (g << 3) + slot);
            uint4 v = *(const uint4*)(xb + (size_t)sg * D + fc);
            b[0] += bf_lo(v.x); b[1] += bf_hi(v.x);
            b[2] += bf_lo(v.y); b[3] += bf_hi(v.y);
            b[4] += bf_lo(v.z); b[5] += bf_hi(v.z);
            b[6] += bf_lo(v.w); b[7] += bf_hi(v.w);
        }
    }

    // main accumulation: mask-free adds
    a[0] += bf_lo(vA0.x) + bf_lo(vA1.x) + bf_lo(vA2.x);
    a[1] += bf_hi(vA0.x) + bf_hi(vA1.x) + bf_hi(vA2.x);
    a[2] += bf_lo(vA0.y) + bf_lo(vA1.y) + bf_lo(vA2.y);
    a[3] += bf_hi(vA0.y) + bf_hi(vA1.y) + bf_hi(vA2.y);
    a[4] += bf_lo(vA0.z) + bf_lo(vA1.z) + bf_lo(vA2.z);
    a[5] += bf_hi(vA0.z) + bf_hi(vA1.z) + bf_hi(vA2.z);
    a[6] += bf_lo(vA0.w) + bf_lo(vA1.w) + bf_lo(vA2.w);
    a[7] += bf_hi(vA0.w) + bf_hi(vA1.w) + bf_hi(vA2.w);

    b[0] += bf_lo(vB0.x) + bf_lo(vB1.x) + bf_lo(vB2.x);
    b[1] += bf_hi(vB0.x) + bf_hi(vB1.x) + bf_hi(vB2.x);
    b[2] += bf_lo(vB0.y) + bf_lo(vB1.y) + bf_lo(vB2.y);
    b[3] += bf_hi(vB0.y) + bf_hi(vB1.y) + bf_hi(vB2.y);
    b[4] += bf_lo(vB0.z) + bf_lo(vB1.z) + bf_lo(vB2.z);
    b[5] += bf_hi(vB0.z) + bf_hi(vB1.z) + bf_hi(vB2.z);
    b[6] += bf_lo(vB0.w) + bf_lo(vB1.w) + bf_lo(vB2.w);
    b[7] += bf_hi(vB0.w) + bf_hi(vB1.w) + bf_hi(vB2.w);

    #pragma unroll
    for (int m = 8; m <= 32; m <<= 1) {
        #pragma unroll
        for (int q = 0; q < 8; ++q) { a[q] += __shfl_xor(a[q], m); b[q] += __shfl_xor(b[q], m); }
    }
    if (slot == 0) {
        uint4 o;
        o.x = (unsigned)f2bf(a[0]) | ((unsigned)f2bf(a[1]) << 16);
        o.y = (unsigned)f2bf(a[2]) | ((unsigned)f2bf(a[3]) << 16);
        o.z = (unsigned)f2bf(a[4]) | ((unsigned)f2bf(a[5]) << 16);
        o.w = (unsigned)f2bf(a[6]) | ((unsigned)f2bf(a[7]) << 16);
        *(uint4*)(aggb + (size_t)n0 * D + fc) = o;
        o.x = (unsigned)f2bf(b[0]) | ((unsigned)f2bf(b[1]) << 16);
        o.y = (unsigned)f2bf(b[2]) | ((unsigned)f2bf(b[3]) << 16);
        o.z = (unsigned)f2bf(b[4]) | ((unsigned)f2bf(b[5]) << 16);
        o.w = (unsigned)f2bf(b[6]) | ((unsigned)f2bf(b[7]) << 16);
        *(uint4*)(aggb + (size_t)n1 * D + fc) = o;
    }
}

// out = tanh(h @ W1 + b1) @ W2 + b2 via mfma_f32_16x16x32_bf16.
// R23: bf16 path writes 0 for pad rows (row >= n_nodes) so x1b pad rows stay
// zero — required by the PADIDX trick in layer-1 gather.
template <bool WRITE_BF16>
__global__ __launch_bounds__(256) void gin_dense_mfma(
    const unsigned short* __restrict__ hb, int n_nodes,
    const unsigned short* __restrict__ w1t, const float* __restrict__ b1,
    const unsigned short* __restrict__ w2t, const float* __restrict__ b2,
    float* __restrict__ out_f, unsigned short* __restrict__ out_b)
{
    __shared__ unsigned short sh [64][72];
    __shared__ unsigned short st [64][72];
    __shared__ unsigned short sw1[64][72];
    __shared__ unsigned short sw2[64][72];

    const int t    = threadIdx.x;
    const int lane = t & 63;
    const int wave = t >> 6;
    const int quad = lane >> 4;
    const int col  = lane & 15;
    const int nb   = blockIdx.x * 64;

    for (int c = t; c < 512; c += 256) {
        int row = c >> 3, c8 = (c & 7) << 3;
        *(uint4*)&sh [row][c8] = *(const uint4*)(hb  + (size_t)(nb + row) * D + c8);
        *(uint4*)&sw1[row][c8] = *(const uint4*)(w1t + row * D + c8);
        *(uint4*)&sw2[row][c8] = *(const uint4*)(w2t + row * D + c8);
    }
    __syncthreads();

    const int arow = 16 * wave + col;
    const int koff = quad << 3;

    short8 a0 = *(const short8*)&sh[arow][koff];
    short8 a1 = *(const short8*)&sh[arow][32 + koff];

    #pragma unroll
    for (int nt = 0; nt < 4; ++nt) {
        int n = (nt << 4) + col;
        short8 bw0 = *(const short8*)&sw1[n][koff];
        short8 bw1 = *(const short8*)&sw1[n][32 + koff];
        float bv = b1[n];
        f32x4 c = {bv, bv, bv, bv};
        c = __builtin_amdgcn_mfma_f32_16x16x32_bf16(a0, bw0, c, 0, 0, 0);
        c = __builtin_amdgcn_mfma_f32_16x16x32_bf16(a1, bw1, c, 0, 0, 0);
        #pragma unroll
        for (int r = 0; r < 4; ++r)
            st[16 * wave + (quad << 2) + r][n] = f2bf(tanhf(c[r]));
    }
    // no __syncthreads: each wave reads back exactly the rows it wrote

    short8 p0 = *(const short8*)&st[arow][koff];
    short8 p1 = *(const short8*)&st[arow][32 + koff];

    #pragma unroll
    for (int nt = 0; nt < 4; ++nt) {
        int n = (nt << 4) + col;
        short8 bw0 = *(const short8*)&sw2[n][koff];
        short8 bw1 = *(const short8*)&sw2[n][32 + koff];
        float bv = b2[n];
        f32x4 c = {bv, bv, bv, bv};
        c = __builtin_amdgcn_mfma_f32_16x16x32_bf16(p0, bw0, c, 0, 0, 0);
        c = __builtin_amdgcn_mfma_f32_16x16x32_bf16(p1, bw1, c, 0, 0, 0);
        #pragma unroll
        for (int r = 0; r < 4; ++r) {
            int row = nb + 16 * wave + (quad << 2) + r;
            if (WRITE_BF16) {
                out_b[(size_t)row * D + n] = (row < n_nodes) ? f2bf(c[r])
                                                             : (unsigned short)0;
            } else if (row < n_nodes) {
                out_f[(size_t)row * D + n] = c[r];
            }
        }
    }
}

extern "C" void kernel_launch(void* const* d_in, const int* in_sizes, int n_in,
                              void* d_out, int out_size, void* d_ws, size_t ws_size,
                              hipStream_t stream)
{
    const float* x    = (const float*)d_in[0];
    const int*   src  = (const int*)  d_in[1];
    const int*   dst  = (const int*)  d_in[2];
    const float* w1_0 = (const float*)d_in[3];
    const float* b1_0 = (const float*)d_in[4];
    const float* w2_0 = (const float*)d_in[5];
    const float* b2_0 = (const float*)d_in[6];
    const float* w1_1 = (const float*)d_in[7];
    const float* b1_1 = (const float*)d_in[8];
    const float* w2_1 = (const float*)d_in[9];
    const float* b2_1 = (const float*)d_in[10];
    float* out = (float*)d_out;

    const int n_nodes = in_sizes[0] / D;        // 50000
    const int n_edges = in_sizes[1];            // 800000
    const int n_pad   = (n_nodes + 63) & ~63;   // 50048
    const int S       = n_pad >> 6;             // 782 slices of 64 nodes
    const int chunk   = (n_edges + NB - 1) / NB;   // 3125

    // ws: hist | off | gcur | elog | buf | aggb | xb | x1b | wt
    int*            hist = (int*)d_ws;
    int*            off  = hist + (size_t)NB * S;
    unsigned*       gcur = (unsigned*)(off + (size_t)NB * S);
    unsigned*       elog = gcur + S;
    unsigned short* buf  = (unsigned short*)(elog + (size_t)S * LSLOT);
    unsigned short* aggb = buf  + (size_t)n_pad * CAP;
    unsigned short* xb   = aggb + (size_t)n_pad * D;
    unsigned short* x1b  = xb   + (size_t)n_pad * D;
    unsigned short* wt   = x1b  + (size_t)n_pad * D;

    const int n4  = n_nodes * D / 4;             // 800000
    const int n4p = n_pad * D / 4;               // 800768 (pad rows zeroed)
    const int ncb = (n4p + 255) / 256;

    count_conv_prep<<<NB + ncb + 64, 256, 0, stream>>>(
        dst, hist, n_edges, chunk, S,
        x, xb, n4, n4p, ncb,
        w1_0, w2_0, w1_1, w2_1, wt);
    prefix_kernel<<<S, 256, 0, stream>>>(hist, off, gcur, S);
    emit_kernel<<<NB, 256, 0, stream>>>(src, dst, off, elog, n_edges, chunk, S);
    bucketize_kernel<<<S, 256, 0, stream>>>(gcur, elog, buf, n_nodes);

    const int gather_blocks = n_pad / 8;      // 6256 (2 nodes/wave)
    const int dense_blocks  = n_pad / 64;     // 782

    // layer 0
    gather_kernel<<<gather_blocks, 256, 0, stream>>>(xb, buf, aggb, n_nodes);
    gin_dense_mfma<true><<<dense_blocks, 256, 0, stream>>>(
        aggb, n_nodes, wt, b1_0, wt + 4096, b2_0, nullptr, x1b);
    // layer 1
    gather_kernel<<<gather_blocks, 256, 0, stream>>>(x1b, buf, aggb, n_nodes);
    gin_dense_mfma<false><<<dense_blocks, 256, 0, stream>>>(
        aggb, n_nodes, wt + 8192, b1_1, wt + 12288, b2_1, out, nullptr);
}